// Round 9
// baseline (212.664 us; speedup 1.0000x reference)
//
#include <hip/hip_runtime.h>

typedef _Float16 half8 __attribute__((ext_vector_type(8)));
typedef float f32x4 __attribute__((ext_vector_type(4)));
typedef float f32x16 __attribute__((ext_vector_type(16)));
typedef unsigned int u32x4 __attribute__((ext_vector_type(4)));

#define NPTS 1024
#define NB 8
#define HDIM 512
#define CH 16

// workspace byte offsets
#define OFF_WBF 0u                  // 8*64*512*16 = 4 MB
#define OFF_WLF 4194304u            // 16 KB
#define OFF_PP  4210688u            // 8*33*512 floats = 540,672 B
#define OFF_IS  4751360u            // 8 floats (+pad)
#define OFF_BX  4751424u            // 128 floats
#define OFF_GC  4751936u            // 264 group counters + 1 global counter

__device__ __forceinline__ float elu(float z) { return z > 0.f ? z : expm1f(z); }

// ---------- kPrep ----------
// blocks 0..1023 : Wb -> f16 octets [i*64+koct][n][8], 1 octet/thread
// block 1024     : Wlast -> octets [hoct][ch][8]; zero Isum/basisx/gc/gcnt
// blocks 1025+   : zero Pp
__global__ __launch_bounds__(256) void kPrep(const float* __restrict__ Wb,
    const float* __restrict__ Wlast,
    _Float16* __restrict__ Wbf, _Float16* __restrict__ Wlf,
    float* __restrict__ Pp, float* __restrict__ Isum,
    float* __restrict__ basisx, unsigned* __restrict__ gc) {
  __shared__ __align__(16) float sm[8192];
  int b = blockIdx.x, t = threadIdx.x;
  if (b < 1024) {
    int i = b >> 7, koct = (b >> 1) & 63, n = (b & 1) * 256 + t;
    const float* src = Wb + ((size_t)i * 512 + koct * 8) * 512 + n;
    float v[8];
#pragma unroll
    for (int j = 0; j < 8; ++j) v[j] = src[j * 512];
    union { _Float16 h[8]; u32x4 u; } hu;
#pragma unroll
    for (int j = 0; j < 8; ++j) hu.h[j] = (_Float16)v[j];
    *(u32x4*)(Wbf + ((size_t)(i * 64 + koct) * 512 + n) * 8) = hu.u;
  } else if (b == 1024) {
    if (t < 8) Isum[t] = 0.f;
    if (t < 128) basisx[t] = 0.f;
    gc[t] = 0u;
    if (t < 9) gc[256 + t] = 0u;       // gc[256..263] + gcnt at gc[264]
#pragma unroll
    for (int it = 0; it < 32; ++it) sm[t + 256 * it] = Wlast[t + 256 * it];
    __syncthreads();
#pragma unroll
    for (int p = 0; p < 4; ++p) {
      int oi = p * 256 + t;
      int ko = oi >> 4, ch = oi & 15;
      union { _Float16 h[8]; u32x4 u; } hu;
#pragma unroll
      for (int jj = 0; jj < 8; ++jj) hu.h[jj] = (_Float16)sm[(ko * 8 + jj) * 16 + ch];
      *(u32x4*)(Wlf + oi * 8) = hu.u;
    }
  } else {
    int o4 = (b - 1025) * 256 + t;     // f32x4 index
    if (o4 < 33792) {                  // 135168/4
      f32x4 z; z[0] = 0.f; z[1] = 0.f; z[2] = 0.f; z[3] = 0.f;
      *(f32x4*)&Pp[o4 * 4] = z;
    }
  }
}

// ---------- kB: fused a0 + GEMM + elu + proj + group-reduce + mu + combine ----------
// grid 1056 = i(8,==XCD) x mt(33) x nq(4). Block 256 thr; wave w owns 32m x 32n.
// a0 tile computed in-block into LDS; B via R5's 4-slot distance-3 register pipeline.
__global__ __launch_bounds__(256, 4) void kB(const _Float16* __restrict__ Wbf,
    const _Float16* __restrict__ Wlf, const float* __restrict__ s,
    const float* __restrict__ x, const float* __restrict__ Wfirst,
    const float* __restrict__ bfirst, const float* __restrict__ Wf,
    const float* __restrict__ bf, const float* __restrict__ bb,
    const float* __restrict__ blast, float* __restrict__ Pp,
    float* __restrict__ Isum, float* __restrict__ basisx,
    unsigned* __restrict__ gc, float* __restrict__ out) {
  __shared__ __align__(16) char LB[32768 + 2048 + 256];  // A octets | S2/sv | misc
  float* S2f   = (float*)(LB + 32768);                   // 512 floats (also sv staging)
  float* wsum  = (float*)(LB + 34816);
  float* muL   = (float*)(LB + 34880);
  unsigned* ocp  = (unsigned*)(LB + 34944);
  unsigned* ocgp = (unsigned*)(LB + 34948);
  const u32x4* Ald = (const u32x4*)LB;

  int t = threadIdx.x, b = blockIdx.x;
  int i = b & 7, r = b >> 3;
  int nq = r & 3, mt = r >> 2;
  int m0 = mt * 32;
  int w = t >> 6, lane = t & 63, ln = lane & 31, q = lane >> 5, q4 = lane >> 4;
  int nw = nq * 128 + w * 32;
  int nb = nw + ln, ib = i * 64;
  const u32x4* b4 = (const u32x4*)Wbf;

  // ---- stage s rows (32 x 8) into S2 region ----
  {
    int m = m0 + (t >> 3), d = t & 7;
    S2f[t] = (m < 1024) ? s[m * 8 + d] : (m == 1024 ? x[d] : 0.f);
  }

  // ---- B pipeline preload (slots 0..2), overlaps a0 compute ----
  u32x4 pb[4][2];
#pragma unroll
  for (int st = 0; st < 3; ++st) {
    int k0 = st * 4 + q, k1 = k0 + 2;
    pb[st][0] = b4[(size_t)(ib + k0) * 512 + nb];
    pb[st][1] = b4[(size_t)(ib + k1) * 512 + nb];
  }
  __syncthreads();

  // ---- compute a0 tile -> A LDS [koct][m][8] ----
  {
    int ml = t & 31, hq = t >> 5;
    int hb = hq * 64;
    float sr[8];
#pragma unroll
    for (int d = 0; d < 8; ++d) sr[d] = S2f[ml * 8 + d];
#pragma unroll
    for (int oj = 0; oj < 8; ++oj) {
      int h0 = hb + oj * 8;
      float a[8];
      f32x4 b0 = *(const f32x4*)&bfirst[h0];
      f32x4 b1 = *(const f32x4*)&bfirst[h0 + 4];
#pragma unroll
      for (int e = 0; e < 4; ++e) { a[e] = b0[e]; a[4 + e] = b1[e]; }
#pragma unroll
      for (int d = 0; d < 8; ++d) {
        float sd = sr[d];
        f32x4 w0 = *(const f32x4*)&Wfirst[d * 512 + h0];
        f32x4 w1 = *(const f32x4*)&Wfirst[d * 512 + h0 + 4];
#pragma unroll
        for (int e = 0; e < 4; ++e) { a[e] += sd * w0[e]; a[4 + e] += sd * w1[e]; }
      }
      union { _Float16 h[8]; u32x4 u; } hu;
#pragma unroll
      for (int e = 0; e < 8; ++e) hu.h[e] = (_Float16)elu(a[e]);
      ((u32x4*)LB)[(hq * 8 + oj) * 32 + ml] = hu.u;
    }
  }
  __syncthreads();

  // ---- K-loop: A from LDS, B 4-slot distance-3 register pipeline ----
  f32x16 acc;
#pragma unroll
  for (int rr = 0; rr < 16; ++rr) acc[rr] = 0.f;
#pragma unroll
  for (int ks = 0; ks < 16; ++ks) {
    int sl = ks & 3;
    int k0 = ks * 4 + q, k1 = k0 + 2;
    half8 aH0 = __builtin_bit_cast(half8, Ald[k0 * 32 + ln]);
    half8 aH1 = __builtin_bit_cast(half8, Ald[k1 * 32 + ln]);
    acc = __builtin_amdgcn_mfma_f32_32x32x16_f16(aH0, __builtin_bit_cast(half8, pb[sl][0]), acc, 0, 0, 0);
    acc = __builtin_amdgcn_mfma_f32_32x32x16_f16(aH1, __builtin_bit_cast(half8, pb[sl][1]), acc, 0, 0, 0);
    if (ks < 13) {
      int sn = (ks + 3) & 3;
      int kn0 = (ks + 3) * 4 + q, kn1 = kn0 + 2;
      pb[sn][0] = b4[(size_t)(ib + kn0) * 512 + nb];
      pb[sn][1] = b4[(size_t)(ib + kn1) * 512 + nb];
    }
  }
  __syncthreads();                       // all A reads done; reuse A region + S2

  // ---- epilogue: bias+elu -> f16 A-frags (per-wave scratch in A region), project ----
  S2f[t] = 0.f;
  S2f[t + 256] = 0.f;
  float bcol = bb[i * 512 + nw + ln];
  _Float16* scr = (_Float16*)(LB + w * 2048);
#pragma unroll
  for (int rr = 0; rr < 16; ++rr) {
    int row = (rr & 3) + 8 * (rr >> 2) + 4 * q;               // 32x32 C-layout row
    float a1 = elu(acc[rr] + bcol);
    int oi = (row >> 4) * 64 + (ln >> 3) * 16 + (row & 15);   // [mt2][koct][m16]
    scr[oi * 8 + (ln & 7)] = (_Float16)a1;
  }
  __syncthreads();

  const u32x4* s4 = (const u32x4*)(LB + w * 2048);
  const u32x4* w4 = (const u32x4*)Wlf;
  int ch = lane & 15;
  half8 wv = __builtin_bit_cast(half8, w4[(size_t)((nw >> 3) + q4) * 16 + ch]);
  float (*S2)[16] = (float(*)[16])S2f;
#pragma unroll
  for (int mt2 = 0; mt2 < 2; ++mt2) {
    f32x4 D2;
#pragma unroll
    for (int rr = 0; rr < 4; ++rr) D2[rr] = 0.f;
    half8 pv = __builtin_bit_cast(half8, s4[mt2 * 64 + q4 * 16 + ch]);
    D2 = __builtin_amdgcn_mfma_f32_16x16x32_f16(pv, wv, D2, 0, 0, 0);
#pragma unroll
    for (int rr = 0; rr < 4; ++rr)
      atomicAdd(&S2[mt2 * 16 + q4 * 4 + rr][ch], D2[rr]);
  }
  __syncthreads();

  // ---- accumulate this n-slice into the (i,mt) Pp tile ----
  float* pp = Pp + (size_t)(i * 33 + mt) * 512;
#pragma unroll
  for (int p = 0; p < 2; ++p) atomicAdd(&pp[t + 256 * p], S2f[t + 256 * p]);
  __threadfence();
  if (t == 0) *ocp = atomicAdd(&gc[mt * 8 + i], 1u);
  __syncthreads();

  if (*ocp == 3) {                       // group finisher: full rows available
    __threadfence();
    if (mt == 32) {
      if (t < 16) atomicAdd(&basisx[i * 16 + t], atomicAdd(&pp[t], 0.f) + blast[t]);
    } else {
      float loc = 0.f;
#pragma unroll
      for (int p = 0; p < 2; ++p) {
        int o = t + 256 * p;
        int ml = o >> 4, c2 = o & 15;
        int gm = m0 + ml;
        float fs = bf[c2];
#pragma unroll
        for (int d = 0; d < 8; ++d) fs += s[gm * 8 + d] * Wf[d * 16 + c2];
        float bs = atomicAdd(&pp[o], 0.f) + blast[c2];
        float dd = fs - bs;
        loc += dd * dd;
      }
      loc += __shfl_xor(loc, 1, 64);
      loc += __shfl_xor(loc, 2, 64);
      loc += __shfl_xor(loc, 4, 64);
      loc += __shfl_xor(loc, 8, 64);
      loc += __shfl_xor(loc, 16, 64);
      loc += __shfl_xor(loc, 32, 64);
      if (lane == 0) wsum[w] = loc;
      __syncthreads();
      if (t == 0) atomicAdd(&Isum[i], wsum[0] + wsum[1] + wsum[2] + wsum[3]);
    }
    __threadfence();
    if (t == 0) *ocgp = atomicAdd(&gc[264], 1u);
    __syncthreads();
    if (*ocgp == 263) {                  // last group finisher: mu + combine
      __threadfence();
      if (t < 8) {
        float S = atomicAdd(&Isum[t], 0.f);
        float nbv = 0.5f * sqrtf(S);     // sqrt(VOLUME/NPTS * S) = sqrt(S/4)
        muL[t] = (nbv <= 1000.0f) ? nbv : 0.f;
      }
      __syncthreads();
      if (t < 128) {
        int c2 = t & 15;
        float num = 0.f, den = 1e-7f;
#pragma unroll
        for (int ii = 0; ii < NB; ++ii) {
          float bx = atomicAdd(&basisx[ii * 16 + c2], 0.f);
          num += muL[ii] * bx;
          den += muL[ii];
        }
        out[t] = num / den;
      }
    }
  }
}

extern "C" void kernel_launch(void* const* d_in, const int* in_sizes, int n_in,
                              void* d_out, int out_size, void* d_ws, size_t ws_size,
                              hipStream_t stream) {
  const float* s      = (const float*)d_in[0];
  const float* x      = (const float*)d_in[1];
  const float* Wfirst = (const float*)d_in[2];
  const float* bfirst = (const float*)d_in[3];
  const float* Wb     = (const float*)d_in[4];
  const float* bb     = (const float*)d_in[5];
  const float* Wlast  = (const float*)d_in[6];
  const float* blast  = (const float*)d_in[7];
  const float* Wf     = (const float*)d_in[8];
  const float* bf     = (const float*)d_in[9];

  char* ws = (char*)d_ws;
  _Float16* Wbf = (_Float16*)(ws + OFF_WBF);
  _Float16* Wlf = (_Float16*)(ws + OFF_WLF);
  float* Pp     = (float*)(ws + OFF_PP);
  float* Isum   = (float*)(ws + OFF_IS);
  float* basisx = (float*)(ws + OFF_BX);
  unsigned* gc  = (unsigned*)(ws + OFF_GC);
  float* out    = (float*)d_out;

  kPrep<<<1157, 256, 0, stream>>>(Wb, Wlast, Wbf, Wlf, Pp, Isum, basisx, gc);
  kB<<<1056, 256, 0, stream>>>(Wbf, Wlf, s, x, Wfirst, bfirst, Wf, bf, bb, blast,
                               Pp, Isum, basisx, gc, out);
}

// Round 10
// 132.747 us; speedup vs baseline: 1.6020x; 1.6020x over previous
//
#include <hip/hip_runtime.h>

typedef _Float16 half8 __attribute__((ext_vector_type(8)));
typedef float f32x4 __attribute__((ext_vector_type(4)));
typedef float f32x16 __attribute__((ext_vector_type(16)));
typedef unsigned int u32x4 __attribute__((ext_vector_type(4)));

#define NPTS 1024
#define NB 8
#define HDIM 512
#define CH 16
#define RT 1056              // 1024 pts + row 1024 = x + zero pad to 33*32

// workspace byte offsets
#define OFF_WBF 0u                         // 8*64*512*16 = 4 MB
#define OFF_A0F 4194304u                   // 64*RT*16 = 1,081,344
#define OFF_WLF 5275648u                   // 16 KB
#define OFF_FS  5292032u                   // 64 KB
#define OFF_IS  5357568u                   // 8 floats
#define OFF_BX  5357632u                   // 128 floats
#define OFF_PZ  5358144u                   // 264*2*4*4096 f32 = 34.6 MB

__device__ __forceinline__ float elu(float z) { return z > 0.f ? z : expm1f(z); }

// ---------- kPrep ----------
// blocks 0..1023   : Wb -> f16 octets [i*64+koct][n][8], 1 octet/thread
// blocks 1024..1287: a0 rows (4/block): elu(s@Wfirst+b) -> octets [koct][m][8]; f_s
// block 1288       : Wlast -> octets [hoct][ch][8]; zero Isum
__global__ __launch_bounds__(256) void kPrep(const float* __restrict__ s,
    const float* __restrict__ x, const float* __restrict__ Wfirst,
    const float* __restrict__ bfirst, const float* __restrict__ Wb,
    const float* __restrict__ Wlast, const float* __restrict__ Wf,
    const float* __restrict__ bf,
    _Float16* __restrict__ Wbf, _Float16* __restrict__ Wlf,
    _Float16* __restrict__ a0f, float* __restrict__ f_s,
    float* __restrict__ Isum) {
  __shared__ __align__(16) float sm[8192];
  int b = blockIdx.x, t = threadIdx.x;
  if (b < 1024) {
    int i = b >> 7, koct = (b >> 1) & 63, n = (b & 1) * 256 + t;
    const float* src = Wb + ((size_t)i * 512 + koct * 8) * 512 + n;
    float v[8];
#pragma unroll
    for (int j = 0; j < 8; ++j) v[j] = src[j * 512];
    union { _Float16 h[8]; u32x4 u; } hu;
#pragma unroll
    for (int j = 0; j < 8; ++j) hu.h[j] = (_Float16)v[j];
    *(u32x4*)(Wbf + ((size_t)(i * 64 + koct) * 512 + n) * 8) = hu.u;
  } else if (b < 1288) {
    int rr = t >> 6, tl = t & 63;
    int m = (b - 1024) * 4 + rr;
    float* sv = &sm[rr * 8];
    if (tl < 8) sv[tl] = (m < 1024) ? s[m * 8 + tl] : (m == 1024 ? x[tl] : 0.f);
    __syncthreads();
    size_t o = ((size_t)tl * RT + m) * 8;
    if (m <= 1024) {
      float acc[8];
#pragma unroll
      for (int jj = 0; jj < 8; ++jj) acc[jj] = bfirst[8 * tl + jj];
#pragma unroll
      for (int d = 0; d < 8; ++d) {
        float sd = sv[d];
        f32x4 w0 = *(const f32x4*)&Wfirst[d * 512 + 8 * tl];
        f32x4 w1 = *(const f32x4*)&Wfirst[d * 512 + 8 * tl + 4];
#pragma unroll
        for (int e = 0; e < 4; ++e) { acc[e] += sd * w0[e]; acc[4 + e] += sd * w1[e]; }
      }
      union { _Float16 h[8]; u32x4 u; } hu;
#pragma unroll
      for (int jj = 0; jj < 8; ++jj) hu.h[jj] = (_Float16)elu(acc[jj]);
      *(u32x4*)(a0f + o) = hu.u;
      if (m < 1024 && tl < 16) {
        float a = bf[tl];
#pragma unroll
        for (int d = 0; d < 8; ++d) a += sv[d] * Wf[d * 16 + tl];
        f_s[m * 16 + tl] = a;
      }
    } else {
      u32x4 z;
#pragma unroll
      for (int e = 0; e < 4; ++e) z[e] = 0u;
      *(u32x4*)(a0f + o) = z;
    }
  } else {
    if (t < 8) Isum[t] = 0.f;
#pragma unroll
    for (int it = 0; it < 32; ++it) sm[t + 256 * it] = Wlast[t + 256 * it];
    __syncthreads();
#pragma unroll
    for (int p = 0; p < 4; ++p) {
      int oi = p * 256 + t;
      int ko = oi >> 4, ch = oi & 15;
      union { _Float16 h[8]; u32x4 u; } hu;
#pragma unroll
      for (int jj = 0; jj < 8; ++jj) hu.h[jj] = (_Float16)sm[(ko * 8 + jj) * 16 + ch];
      *(u32x4*)(Wlf + oi * 8) = hu.u;
    }
  }
}

// ---------- kB: f16 MFMA GEMM, K-split x2, raw z-partial output ----------
// grid 2112 = i(8,==XCD) x kq(2) x nq(4) x mt(33). Block 256 thr; wave: 32m x 32n,
// K=256 (8 macro-iters, 4-slot distance-3 register pipeline). No LDS, no barriers.
__global__ __launch_bounds__(256, 4) void kB(const _Float16* __restrict__ Wbf,
    const _Float16* __restrict__ a0f, float* __restrict__ Pz) {
  int t = threadIdx.x, b = blockIdx.x;
  int i = b & 7, kq = (b >> 3) & 1, r = b >> 4;
  int nq = r & 3, mt = r >> 2;
  int m0 = mt * 32;
  int w = t >> 6, lane = t & 63, ln = lane & 31, q = lane >> 5;
  int nw = nq * 128 + w * 32;

  const u32x4* a4 = (const u32x4*)a0f;
  const u32x4* b4 = (const u32x4*)Wbf;
  int ma = m0 + ln, nb = nw + ln;
  int ib = i * 64 + kq * 32;     // B koct base
  int ka = kq * 32;              // A koct base

  f32x16 acc;
#pragma unroll
  for (int rr = 0; rr < 16; ++rr) acc[rr] = 0.f;

  u32x4 pa[4][2], pb[4][2];
#pragma unroll
  for (int st = 0; st < 3; ++st) {
    int k0 = st * 4 + q, k1 = k0 + 2;
    pa[st][0] = a4[(ka + k0) * RT + ma];
    pa[st][1] = a4[(ka + k1) * RT + ma];
    pb[st][0] = b4[(size_t)(ib + k0) * 512 + nb];
    pb[st][1] = b4[(size_t)(ib + k1) * 512 + nb];
  }
#pragma unroll
  for (int ks = 0; ks < 8; ++ks) {
    int sl = ks & 3;
    acc = __builtin_amdgcn_mfma_f32_32x32x16_f16(
        __builtin_bit_cast(half8, pa[sl][0]), __builtin_bit_cast(half8, pb[sl][0]), acc, 0, 0, 0);
    acc = __builtin_amdgcn_mfma_f32_32x32x16_f16(
        __builtin_bit_cast(half8, pa[sl][1]), __builtin_bit_cast(half8, pb[sl][1]), acc, 0, 0, 0);
    if (ks < 5) {
      int sn = (ks + 3) & 3;
      int k0 = (ks + 3) * 4 + q, k1 = k0 + 2;
      pa[sn][0] = a4[(ka + k0) * RT + ma];
      pa[sn][1] = a4[(ka + k1) * RT + ma];
      pb[sn][0] = b4[(size_t)(ib + k0) * 512 + nb];
      pb[sn][1] = b4[(size_t)(ib + k1) * 512 + nb];
    }
  }

  // store raw z-partials (disjoint, plain stores)
  size_t base = ((size_t)((i * 33 + mt) * 2 + kq) * 4 + nq) * 4096 + w * 32 + ln;
#pragma unroll
  for (int rr = 0; rr < 16; ++rr) {
    int row = (rr & 3) + 8 * (rr >> 2) + 4 * q;   // 32x32 C-layout row
    Pz[base + (size_t)row * 128] = acc[rr];
  }
}

// ---------- kRed: sum kq partials + elu -> f16 frags -> MFMA proj -> diff^2 ----------
// grid 264 = i(8,==XCD) x mt(33). Wave w projects h-chunk w*128..+127.
__global__ __launch_bounds__(256, 2) void kRed(const float* __restrict__ Pz,
    const _Float16* __restrict__ Wlf, const float* __restrict__ bb,
    const float* __restrict__ blast, const float* __restrict__ f_s,
    float* __restrict__ Isum, float* __restrict__ basisx) {
  __shared__ __align__(16) char AL[32768];   // a1 octets [64 koct][32 m][8 f16]
  __shared__ float S2f[512];
  __shared__ float wsum[4];
  int t = threadIdx.x, b = blockIdx.x;
  int i = b & 7, mt = b >> 3;
  int m0 = mt * 32;
  int w = t >> 6, lane = t & 63, q4 = lane >> 4, ch = lane & 15;

  S2f[t] = 0.f;
  S2f[t + 256] = 0.f;

  // phase1: z = sum(kq) + bias -> elu -> f16 octet into AL
  int m = t & 31, og = t >> 5;
  size_t pzb0 = ((size_t)(i * 33 + mt) * 2) * 4 * 4096;
  size_t pzb1 = pzb0 + 4 * 4096;
  u32x4* ALq = (u32x4*)AL;
#pragma unroll
  for (int j = 0; j < 8; ++j) {
    int oct = og + 8 * j;
    int h0 = oct * 8, nq = h0 >> 7, n0 = h0 & 127;
    size_t o0 = (size_t)nq * 4096 + m * 128 + n0;
    f32x4 za0 = *(const f32x4*)&Pz[pzb0 + o0];
    f32x4 za1 = *(const f32x4*)&Pz[pzb0 + o0 + 4];
    f32x4 zb0 = *(const f32x4*)&Pz[pzb1 + o0];
    f32x4 zb1 = *(const f32x4*)&Pz[pzb1 + o0 + 4];
    union { _Float16 h[8]; u32x4 u; } hu;
#pragma unroll
    for (int e = 0; e < 4; ++e) {
      hu.h[e]     = (_Float16)elu(za0[e] + zb0[e] + bb[i * 512 + h0 + e]);
      hu.h[4 + e] = (_Float16)elu(za1[e] + zb1[e] + bb[i * 512 + h0 + 4 + e]);
    }
    ALq[oct * 32 + m] = hu.u;
  }
  __syncthreads();

  // phase2: projection via 16x16x32 MFMA; wave w covers koct w*16..w*16+15
  const u32x4* w4 = (const u32x4*)Wlf;
  float (*S2)[16] = (float(*)[16])S2f;
#pragma unroll
  for (int mt2 = 0; mt2 < 2; ++mt2) {
    f32x4 D2;
#pragma unroll
    for (int rr = 0; rr < 4; ++rr) D2[rr] = 0.f;
#pragma unroll
    for (int ks2 = 0; ks2 < 4; ++ks2) {
      int koct = w * 16 + ks2 * 4 + q4;
      half8 pv = __builtin_bit_cast(half8, ALq[koct * 32 + mt2 * 16 + ch]);
      half8 wv = __builtin_bit_cast(half8, w4[koct * 16 + ch]);
      D2 = __builtin_amdgcn_mfma_f32_16x16x32_f16(pv, wv, D2, 0, 0, 0);
    }
#pragma unroll
    for (int rr = 0; rr < 4; ++rr)
      atomicAdd(&S2[mt2 * 16 + q4 * 4 + rr][ch], D2[rr]);
  }
  __syncthreads();

  if (mt == 32) {
    // x-row is local row 0 (global 1024); rows 1+ are padding
    if (t < 16) basisx[i * 16 + t] = S2[0][t] + blast[t];
    return;
  }
  float loc = 0.f;
#pragma unroll
  for (int p = 0; p < 2; ++p) {
    int o = t + 256 * p;
    int ml = o >> 4, c2 = o & 15;
    float bs = S2[ml][c2] + blast[c2];
    float d = f_s[(size_t)(m0 + ml) * 16 + c2] - bs;
    loc += d * d;
  }
  loc += __shfl_xor(loc, 1, 64);
  loc += __shfl_xor(loc, 2, 64);
  loc += __shfl_xor(loc, 4, 64);
  loc += __shfl_xor(loc, 8, 64);
  loc += __shfl_xor(loc, 16, 64);
  loc += __shfl_xor(loc, 32, 64);
  if (lane == 0) wsum[w] = loc;
  __syncthreads();
  if (t == 0) atomicAdd(&Isum[i], wsum[0] + wsum[1] + wsum[2] + wsum[3]);
}

// ---------- kFin: mu from Isum + weighted combine ----------
__global__ __launch_bounds__(128) void kFin(const float* __restrict__ Isum,
    const float* __restrict__ basisx, float* __restrict__ out) {
  __shared__ float muL[8];
  int t = threadIdx.x;
  if (t < 8) {
    float nb = 0.5f * sqrtf(Isum[t]);   // sqrt(VOLUME/NPTS * S) = sqrt(S/4)
    muL[t] = (nb <= 1000.0f) ? nb : 0.f;
  }
  __syncthreads();
  int ch = t & 15;
  float num = 0.f, den = 1e-7f;
#pragma unroll
  for (int i = 0; i < NB; ++i) {
    num += muL[i] * basisx[i * 16 + ch];
    den += muL[i];
  }
  out[t] = num / den;
}

extern "C" void kernel_launch(void* const* d_in, const int* in_sizes, int n_in,
                              void* d_out, int out_size, void* d_ws, size_t ws_size,
                              hipStream_t stream) {
  const float* s      = (const float*)d_in[0];
  const float* x      = (const float*)d_in[1];
  const float* Wfirst = (const float*)d_in[2];
  const float* bfirst = (const float*)d_in[3];
  const float* Wb     = (const float*)d_in[4];
  const float* bb     = (const float*)d_in[5];
  const float* Wlast  = (const float*)d_in[6];
  const float* blast  = (const float*)d_in[7];
  const float* Wf     = (const float*)d_in[8];
  const float* bf     = (const float*)d_in[9];

  char* ws = (char*)d_ws;
  _Float16* Wbf = (_Float16*)(ws + OFF_WBF);
  _Float16* a0f = (_Float16*)(ws + OFF_A0F);
  _Float16* Wlf = (_Float16*)(ws + OFF_WLF);
  float* f_s    = (float*)(ws + OFF_FS);
  float* Isum   = (float*)(ws + OFF_IS);
  float* basisx = (float*)(ws + OFF_BX);
  float* Pz     = (float*)(ws + OFF_PZ);
  float* out    = (float*)d_out;

  kPrep<<<1289, 256, 0, stream>>>(s, x, Wfirst, bfirst, Wb, Wlast, Wf, bf,
                                  Wbf, Wlf, a0f, f_s, Isum);
  kB<<<2112, 256, 0, stream>>>(Wbf, a0f, Pz);
  kRed<<<264, 256, 0, stream>>>(Pz, Wlf, bb, blast, f_s, Isum, basisx);
  kFin<<<1, 128, 0, stream>>>(Isum, basisx, out);
}